// Round 16
// baseline (76.583 us; speedup 1.0000x reference)
//
#include <hip/hip_runtime.h>
#include <math.h>

#define NB 8
#define NT 2048
#define NC 1024
#define DK 64
#define BT (NB*NT)

// ws layout: QKV bf16 (6,291,456 B) | attention partials (1120 slots x 8704 B)
#define QKV_BYTES  (3u * BT * DK * 2u)
#define SLOT_BYTES 8704u   // Obf[64][64] bf16 (8192) + m f32[64] (256) + l f32[64] (256)

typedef unsigned short ushort_t;
typedef unsigned int uint_t;
typedef __attribute__((ext_vector_type(8))) short short8;
typedef __attribute__((ext_vector_type(4))) float f32x4;

__device__ __forceinline__ float bf2f(uint_t u) {
    union { uint_t i; float f; } v;
    v.i = u << 16;
    return v.f;
}
__device__ __forceinline__ ushort_t f2bf(float f) {
    union { float f; uint_t i; } v; v.f = f;
    uint_t x = v.i;
    return (ushort_t)((x + 0x7fffu + ((x >> 16) & 1u)) >> 16);
}
__device__ __forceinline__ uint_t pack2bf(float lo, float hi) {
    return (uint_t)f2bf(lo) | ((uint_t)f2bf(hi) << 16);
}

// slot prefix within a batch for q-tile qt (qt>=4): sum of nseg over q'=4..qt-1,
// nseg(q') = q'/4 + 1.  140 slots per batch total.
__device__ __forceinline__ int seg_prefix(int qt) {
    const int a = qt >> 2;
    return 2 * a * (a + 1) - 4 + (qt & 3) * (a + 1);
}

// ---------------------------------------------------------------------------
// Kernel 0: W fragment-pack prep (r14 layout, unchanged): 384 KB in d_out.
// ---------------------------------------------------------------------------
__global__ __launch_bounds__(256) void wt_prep_kernel(
    const float* __restrict__ Wq, const float* __restrict__ Wk,
    const float* __restrict__ Wv, ushort_t* __restrict__ WtP)
{
    const int tid = blockIdx.x * 256 + threadIdx.x;   // 0..24575
    int idx = tid;
    const int lane = idx & 63;  idx >>= 6;
    const int j    = idx % 6;   idx /= 6;
    const int w    = idx & 3;   idx >>= 2;
    const int ks   = idx & 7;   idx >>= 3;
    const int grp  = idx & 1;

    const int col = lane & 15;
    const int g   = lane >> 4;
    const int tj  = j >> 1;
    const int c   = j & 1;
    const int ng  = 48 * w + 16 * tj + col;
    const int which = ng >> 6, ncol = ng & 63;
    const float* W = (which == 0) ? Wq : (which == 1) ? Wk : Wv;
    const int kb = grp * 512 + ks * 64 + 32 * c + 8 * g;

    ushort_t o[8];
    #pragma unroll
    for (int i = 0; i < 8; ++i) o[i] = f2bf(W[(size_t)(kb + i) * DK + ncol]);
    *reinterpret_cast<uint4*>(&WtP[(size_t)tid * 8]) = *reinterpret_cast<uint4*>(o);
}

// ---------------------------------------------------------------------------
// Kernel 1: QKV projection on MFMA — r16: BARRIER-FREE main loop.
// A-fragments loaded DIRECTLY from global X in frag layout (32B contiguous
// per lane per frag-half; wave = 16 full 128B cache lines, coalesced; 4
// column-waves issue identical addresses -> L1 dedup).  f32->bf16 cvt
// in-register.  No LDS X staging, no per-step barriers — waves slip freely
// (r15's null falsified prefetch-depth; suspect was the per-step barrier
// convoy on worst-case HBM latency).
// ---------------------------------------------------------------------------
__global__ __launch_bounds__(512, 4) void qkv_mfma_kernel(
    const float* __restrict__ X, const ushort_t* __restrict__ WtP,
    const float* __restrict__ bq, const float* __restrict__ bk,
    const float* __restrict__ bv, ushort_t* __restrict__ QKV)
{
    __shared__ float    Racc[32 * 196];      // group-1 partial; later aliased as OutL
    __shared__ ushort_t VtL[64 * 40];

    const int t    = threadIdx.x;
    const int grp  = t >> 8;          // 0,1 : K-half
    const int w    = (t >> 6) & 3;    // col-wave within group
    const int lane = t & 63;
    const int g    = lane >> 4;
    const int col  = lane & 15;
    const int m0   = blockIdx.x * 32;
    const int kb   = grp * 512;

    // per-lane X base pointers, frag layout: row m0+16ri+col, k = kb+32c+8g
    const float* xp00 = X + (size_t)(m0 + col) * NC      + kb + 8 * g;        // ri0 c0
    const float* xp01 = xp00 + 32;                                            // ri0 c1
    const float* xp10 = X + (size_t)(m0 + 16 + col) * NC + kb + 8 * g;        // ri1 c0
    const float* xp11 = xp10 + 32;                                            // ri1 c1

    f32x4 acc[2][3];
    #pragma unroll
    for (int ri = 0; ri < 2; ++ri)
        #pragma unroll
        for (int tj = 0; tj < 3; ++tj) acc[ri][tj] = (f32x4){0.f, 0.f, 0.f, 0.f};

    #pragma unroll
    for (int ks = 0; ks < 8; ++ks) {
        // ---- A frags direct from global (f32 -> bf16 in-register) ----
        short8 af[2][2];
        {
            const float* ps[4] = { xp00 + ks * 64, xp01 + ks * 64,
                                   xp10 + ks * 64, xp11 + ks * 64 };
            #pragma unroll
            for (int q = 0; q < 4; ++q) {
                float4 v0 = reinterpret_cast<const float4*>(ps[q])[0];
                float4 v1 = reinterpret_cast<const float4*>(ps[q])[1];
                ushort_t b[8];
                b[0] = f2bf(v0.x); b[1] = f2bf(v0.y); b[2] = f2bf(v0.z); b[3] = f2bf(v0.w);
                b[4] = f2bf(v1.x); b[5] = f2bf(v1.y); b[6] = f2bf(v1.z); b[7] = f2bf(v1.w);
                af[q >> 1][q & 1] = *reinterpret_cast<const short8*>(b);
            }
        }
        // ---- W frags (fragment-packed, 6 x 1KB coalesced wave-loads) ----
        short8 wf[6];
        {
            const ushort_t* base = WtP + ((size_t)((grp * 8 + ks) * 4 + w)) * (6 * 64 * 8);
            #pragma unroll
            for (int j = 0; j < 6; ++j)
                wf[j] = *reinterpret_cast<const short8*>(base + (j * 64 + lane) * 8);
        }
        // ---- MFMA ----
        #pragma unroll
        for (int c = 0; c < 2; ++c)
            #pragma unroll
            for (int ri = 0; ri < 2; ++ri)
                #pragma unroll
                for (int tj = 0; tj < 3; ++tj)
                    acc[ri][tj] = __builtin_amdgcn_mfma_f32_16x16x32_bf16(
                        af[ri][c], wf[tj * 2 + c], acc[ri][tj], 0, 0, 0);
    }

    // ---- merge the two K-halves via LDS (first barriers in the kernel) ----
    __syncthreads();
    if (grp == 1) {
        #pragma unroll
        for (int ri = 0; ri < 2; ++ri)
            #pragma unroll
            for (int tj = 0; tj < 3; ++tj)
                #pragma unroll
                for (int r = 0; r < 4; ++r)
                    Racc[(16 * ri + 4 * g + r) * 196 + 48 * w + 16 * tj + col] =
                        acc[ri][tj][r];
    }
    __syncthreads();
    if (grp == 0) {
        #pragma unroll
        for (int ri = 0; ri < 2; ++ri)
            #pragma unroll
            for (int tj = 0; tj < 3; ++tj)
                #pragma unroll
                for (int r = 0; r < 4; ++r)
                    acc[ri][tj][r] +=
                        Racc[(16 * ri + 4 * g + r) * 196 + 48 * w + 16 * tj + col];
    }

    // ---- fully-coalesced epilogue: bounce Q, K, V through LDS ----
    ushort_t* OutL = reinterpret_cast<ushort_t*>(Racc);   // Racc is dead now

    if (grp == 0) {
        #pragma unroll
        for (int tj = 0; tj < 3; ++tj) {
            const int ng    = 48 * w + 16 * tj + col;
            const int which = ng >> 6, ncol = ng & 63;
            if (which == 2) {
                const float bb = bv[ncol];
                #pragma unroll
                for (int ri = 0; ri < 2; ++ri)
                    #pragma unroll
                    for (int r = 0; r < 4; ++r)
                        VtL[ncol * 40 + 16 * ri + 4 * g + r] = f2bf(acc[ri][tj][r] + bb);
            }
        }
    }

    #pragma unroll
    for (int pass = 0; pass < 2; ++pass) {   // 0: Q, 1: K
        __syncthreads();   // OutL free (prev pass copied / Racc merge done)
        if (grp == 0) {
            #pragma unroll
            for (int tj = 0; tj < 3; ++tj) {
                const int ng    = 48 * w + 16 * tj + col;
                const int which = ng >> 6, ncol = ng & 63;
                if (which == pass) {
                    const float bb = (pass == 0) ? bq[ncol] : bk[ncol];
                    const float qs = (pass == 0) ? 0.125f : 1.0f;
                    #pragma unroll
                    for (int ri = 0; ri < 2; ++ri)
                        #pragma unroll
                        for (int r = 0; r < 4; ++r)
                            OutL[(16 * ri + 4 * g + r) * 72 + ncol] =
                                f2bf((acc[ri][tj][r] + bb) * qs);
                }
            }
        }
        __syncthreads();
        {   // coalesced copy-out: 32 rows x 128B, 512 threads x 8B
            ushort_t* Y = QKV + (size_t)pass * BT * DK;
            const int row = t >> 4;
            const int c4  = (t & 15) * 4;
            ushort4 v = *reinterpret_cast<const ushort4*>(&OutL[row * 72 + c4]);
            *reinterpret_cast<ushort4*>(&Y[(size_t)(m0 + row) * DK + c4]) = v;
        }
    }

    __syncthreads();
    {   // coalesced V^T store: 64 d-rows x 64B, 512 threads x 8B
        ushort_t* Vt = QKV + (size_t)2 * BT * DK;
        const int d  = t >> 3;
        const int sg = t & 7;
        ushort4 v = *reinterpret_cast<const ushort4*>(&VtL[d * 40 + sg * 4]);
        *reinterpret_cast<ushort4*>(&Vt[(size_t)d * BT + m0 + sg * 4]) = v;
    }
}

// ---------------------------------------------------------------------------
// Kernel 2: causal flash attention — k-segment-resident, zero hot-loop
// barriers, 2-way q-tile ILP (round-11 structure, unchanged).
// ---------------------------------------------------------------------------
__global__ __launch_bounds__(256) void attn_seg_kernel(
    const ushort_t* __restrict__ QKV, float* __restrict__ Out,
    char* __restrict__ Pbase)
{
    const ushort_t* Qw = QKV;
    const ushort_t* Kw = QKV + (size_t)BT * DK;
    const ushort_t* Vw = QKV + (size_t)2 * BT * DK;   // [DK][BT]

    __shared__ ushort_t Ks[256 * 72];
    __shared__ ushort_t VtL[64 * 288];

    const int t     = threadIdx.x;
    const int w     = t >> 6;
    const int lane  = t & 63;
    const int g     = lane >> 4;
    const int col   = lane & 15;
    const int batch = blockIdx.x & 7;
    const int u     = blockIdx.x >> 3;   // 0..71

    int s;
    if      (u < 16) s = 0;
    else if (u < 30) s = 1;
    else if (u < 42) s = 2;
    else if (u < 52) s = 3;
    else if (u < 60) s = 4;
    else if (u < 66) s = 5;
    else if (u < 70) s = 6;
    else             s = 7;
    const int off2 = 16 * s - s * (s - 1);
    const int qt0  = 4 * s + 2 * (u - off2);
    const int kbase = 256 * s;
    const int diag0 = qt0 - 4 * s;
    const int ntile = min(4, diag0 + 2);

    {
        const int sr = t >> 2;
        const int ss = t & 3;
        for (int i = 0; i < ntile; ++i) {
            const int krow = 64 * i + sr;
            const size_t gk = ((size_t)(batch * NT) + kbase + krow) * DK + ss * 16;
            const uint4* kp = reinterpret_cast<const uint4*>(Kw + gk);
            *reinterpret_cast<uint4*>(&Ks[krow * 72 + ss * 16])     = kp[0];
            *reinterpret_cast<uint4*>(&Ks[krow * 72 + ss * 16 + 8]) = kp[1];
            const size_t gv = (size_t)sr * BT + (batch * NT + kbase + 64 * i) + ss * 16;
            const uint4* vp = reinterpret_cast<const uint4*>(Vw + gv);
            *reinterpret_cast<uint4*>(&VtL[sr * 288 + 72 * i + ss * 16])     = vp[0];
            *reinterpret_cast<uint4*>(&VtL[sr * 288 + 72 * i + ss * 16 + 8]) = vp[1];
        }
    }
    __syncthreads();   // the ONLY barrier

    const int qrow0 = qt0 * 64 + 16 * w + col;
    const int qrow1 = qrow0 + 64;

    short8 q0a, q0b, q1a, q1b;
    {
        const ushort_t* Qr0 = Qw + ((size_t)(batch * NT) + qrow0) * DK;
        q0a = *reinterpret_cast<const short8*>(Qr0 + 8 * g);
        q0b = *reinterpret_cast<const short8*>(Qr0 + 32 + 8 * g);
        const ushort_t* Qr1 = Qw + ((size_t)(batch * NT) + qrow1) * DK;
        q1a = *reinterpret_cast<const short8*>(Qr1 + 8 * g);
        q1b = *reinterpret_cast<const short8*>(Qr1 + 32 + 8 * g);
    }

    f32x4 Oa0[4], Oa1[4];
    #pragma unroll
    for (int dt = 0; dt < 4; ++dt) {
        Oa0[dt] = (f32x4){0.f, 0.f, 0.f, 0.f};
        Oa1[dt] = (f32x4){0.f, 0.f, 0.f, 0.f};
    }
    float m0 = -INFINITY, l0 = 0.0f;
    float m1 = -INFINITY, l1 = 0.0f;

    for (int ktl = 0; ktl < ntile; ++ktl) {
        f32x4 sa0[4], sa1[4];
        #pragma unroll
        for (int tj = 0; tj < 4; ++tj) {
            sa0[tj] = (f32x4){0.f, 0.f, 0.f, 0.f};
            sa1[tj] = (f32x4){0.f, 0.f, 0.f, 0.f};
        }
        __builtin_amdgcn_s_setprio(1);
        #pragma unroll
        for (int tj = 0; tj < 4; ++tj) {
            const ushort_t* kb = &Ks[(64 * ktl + col + 16 * tj) * 72 + 8 * g];
            short8 kf0 = *reinterpret_cast<const short8*>(kb);
            short8 kf1 = *reinterpret_cast<const short8*>(kb + 32);
            sa0[tj] = __builtin_amdgcn_mfma_f32_16x16x32_bf16(kf0, q0a, sa0[tj], 0, 0, 0);
            sa0[tj] = __builtin_amdgcn_mfma_f32_16x16x32_bf16(kf1, q0b, sa0[tj], 0, 0, 0);
            sa1[tj] = __builtin_amdgcn_mfma_f32_16x16x32_bf16(kf0, q1a, sa1[tj], 0, 0, 0);
            sa1[tj] = __builtin_amdgcn_mfma_f32_16x16x32_bf16(kf1, q1b, sa1[tj], 0, 0, 0);
        }
        __builtin_amdgcn_s_setprio(0);

        const int s0 = kbase + 64 * ktl;
        if (ktl >= diag0) {
            #pragma unroll
            for (int tj = 0; tj < 4; ++tj)
                #pragma unroll
                for (int r = 0; r < 4; ++r)
                    if (s0 + 16 * tj + 4 * g + r > qrow0) sa0[tj][r] = -INFINITY;
        }
        if (ktl >= diag0 + 1) {
            #pragma unroll
            for (int tj = 0; tj < 4; ++tj)
                #pragma unroll
                for (int r = 0; r < 4; ++r)
                    if (s0 + 16 * tj + 4 * g + r > qrow1) sa1[tj][r] = -INFINITY;
        }

        float vx0 = sa0[0][0], vx1 = sa1[0][0];
        #pragma unroll
        for (int tj = 0; tj < 4; ++tj)
            #pragma unroll
            for (int r = 0; r < 4; ++r) {
                vx0 = fmaxf(vx0, sa0[tj][r]);
                vx1 = fmaxf(vx1, sa1[tj][r]);
            }
        vx0 = fmaxf(vx0, __shfl_xor(vx0, 16, 64));
        vx1 = fmaxf(vx1, __shfl_xor(vx1, 16, 64));
        vx0 = fmaxf(vx0, __shfl_xor(vx0, 32, 64));
        vx1 = fmaxf(vx1, __shfl_xor(vx1, 32, 64));

        const float mn0 = fmaxf(m0, vx0);
        const float mn1 = fmaxf(m1, vx1);
        const float sc0 = __expf(m0 - mn0);
        const float sc1 = __expf(m1 - mn1);
        m0 = mn0; m1 = mn1;

        float lt0 = 0.f, lt1 = 0.f;
        #pragma unroll
        for (int tj = 0; tj < 4; ++tj)
            #pragma unroll
            for (int r = 0; r < 4; ++r) {
                sa0[tj][r] = __expf(sa0[tj][r] - mn0);
                sa1[tj][r] = __expf(sa1[tj][r] - mn1);
                lt0 += sa0[tj][r];
                lt1 += sa1[tj][r];
            }
        lt0 += __shfl_xor(lt0, 16, 64);
        lt1 += __shfl_xor(lt1, 16, 64);
        lt0 += __shfl_xor(lt0, 32, 64);
        lt1 += __shfl_xor(lt1, 32, 64);
        l0 = l0 * sc0 + lt0;
        l1 = l1 * sc1 + lt1;

        float sco0[4], sco1[4];
        #pragma unroll
        for (int r = 0; r < 4; ++r) {
            sco0[r] = __shfl(sc0, 20 * g + r, 64);
            sco1[r] = __shfl(sc1, 20 * g + r, 64);
        }
        #pragma unroll
        for (int dt = 0; dt < 4; ++dt)
            #pragma unroll
            for (int r = 0; r < 4; ++r) {
                Oa0[dt][r] *= sco0[r];
                Oa1[dt][r] *= sco1[r];
            }

        uint_t pk00[4], pk01[4], pk10[4], pk11[4];
        #pragma unroll
        for (int tj = 0; tj < 4; ++tj) {
            pk00[tj] = pack2bf(sa0[tj][0], sa0[tj][1]);
            pk01[tj] = pack2bf(sa0[tj][2], sa0[tj][3]);
            pk10[tj] = pack2bf(sa1[tj][0], sa1[tj][1]);
            pk11[tj] = pack2bf(sa1[tj][2], sa1[tj][3]);
        }
        const int sA = col + 32 * (g & 1);
        const int sB = sA + 16;
        const bool hi = (g >= 2);

        #pragma unroll
        for (int c = 0; c < 2; ++c) {
            uint_t a0 = __shfl(pk00[2*c], sA, 64), b0 = __shfl(pk00[2*c+1], sA, 64);
            uint_t a1 = __shfl(pk01[2*c], sA, 64), b1 = __shfl(pk01[2*c+1], sA, 64);
            uint_t a2 = __shfl(pk00[2*c], sB, 64), b2 = __shfl(pk00[2*c+1], sB, 64);
            uint_t a3 = __shfl(pk01[2*c], sB, 64), b3 = __shfl(pk01[2*c+1], sB, 64);
            uint_t c0 = __shfl(pk10[2*c], sA, 64), d0 = __shfl(pk10[2*c+1], sA, 64);
            uint_t c1 = __shfl(pk11[2*c], sA, 64), d1 = __shfl(pk11[2*c+1], sA, 64);
            uint_t c2 = __shfl(pk10[2*c], sB, 64), d2 = __shfl(pk10[2*c+1], sB, 64);
            uint_t c3 = __shfl(pk11[2*c], sB, 64), d3 = __shfl(pk11[2*c+1], sB, 64);
            uint_t pa0[4], pa1[4];
            pa0[0] = hi ? b0 : a0;
            pa0[1] = hi ? b1 : a1;
            pa0[2] = hi ? b2 : a2;
            pa0[3] = hi ? b3 : a3;
            pa1[0] = hi ? d0 : c0;
            pa1[1] = hi ? d1 : c1;
            pa1[2] = hi ? d2 : c2;
            pa1[3] = hi ? d3 : c3;
            short8 paf0 = *reinterpret_cast<const short8*>(pa0);
            short8 paf1 = *reinterpret_cast<const short8*>(pa1);
            __builtin_amdgcn_s_setprio(1);
            #pragma unroll
            for (int dt = 0; dt < 4; ++dt) {
                short8 vf = *reinterpret_cast<const short8*>(
                    &VtL[(col + 16 * dt) * 288 + 72 * ktl + 32 * c + 8 * g]);
                Oa0[dt] = __builtin_amdgcn_mfma_f32_16x16x32_bf16(paf0, vf, Oa0[dt], 0, 0, 0);
                Oa1[dt] = __builtin_amdgcn_mfma_f32_16x16x32_bf16(paf1, vf, Oa1[dt], 0, 0, 0);
            }
            __builtin_amdgcn_s_setprio(0);
        }
    }

    // ---- epilogue, per q-tile ----
    #pragma unroll
    for (int iq = 0; iq < 2; ++iq) {
        const int qt = qt0 + iq;
        const float mm = iq ? m1 : m0;
        const float ll = iq ? l1 : l0;
        const f32x4* Oa = iq ? Oa1 : Oa0;

        float lr[4];
        #pragma unroll
        for (int r = 0; r < 4; ++r) lr[r] = __shfl(ll, 20 * g + r, 64);

        if (qt < 4) {
            #pragma unroll
            for (int r = 0; r < 4; ++r) {
                const float inv = 1.0f / lr[r];
                const int row = qt * 64 + 16 * w + 4 * g + r;
                float* op = Out + ((size_t)(batch * NT) + row) * DK + col;
                #pragma unroll
                for (int dt = 0; dt < 4; ++dt) op[16 * dt] = Oa[dt][r] * inv;
            }
        } else {
            float mr[4];
            #pragma unroll
            for (int r = 0; r < 4; ++r) mr[r] = __shfl(mm, 20 * g + r, 64);
            const int slot = batch * 140 + seg_prefix(qt) + s;
            char* sp = Pbase + (size_t)slot * SLOT_BYTES;
            ushort_t* Ob  = reinterpret_cast<ushort_t*>(sp);
            float*    Pm  = reinterpret_cast<float*>(sp + 8192);
            float*    Plv = reinterpret_cast<float*>(sp + 8448);
            #pragma unroll
            for (int r = 0; r < 4; ++r) {
                const int rloc = 16 * w + 4 * g + r;
                #pragma unroll
                for (int dt = 0; dt < 4; ++dt)
                    Ob[rloc * 64 + 16 * dt + col] = f2bf(Oa[dt][r]);
                if (col == 0) { Pm[rloc] = mr[r]; Plv[rloc] = lr[r]; }
            }
        }
    }
}

// ---------------------------------------------------------------------------
// Kernel 3: combine partial segments (unchanged).
// ---------------------------------------------------------------------------
__global__ __launch_bounds__(256) void attn_combine_kernel(
    const char* __restrict__ Pbase, float* __restrict__ Out)
{
    const int bid   = blockIdx.x;       // 0..223
    const int batch = bid / 28;
    const int qt    = 4 + bid % 28;
    const int nseg  = (qt >> 2) + 1;    // 2..8
    const int slot0 = batch * 140 + seg_prefix(qt);

    const int t   = threadIdx.x;
    const int row = t >> 2;
    const int d0  = (t & 3) * 16;

    float ms[8], ls[8];
    float M = -INFINITY;
    #pragma unroll
    for (int s = 0; s < 8; ++s)
        if (s < nseg) {
            const char* sp = Pbase + (size_t)(slot0 + s) * SLOT_BYTES;
            ms[s] = reinterpret_cast<const float*>(sp + 8192)[row];
            ls[s] = reinterpret_cast<const float*>(sp + 8448)[row];
            M = fmaxf(M, ms[s]);
        }

    float acc[16];
    #pragma unroll
    for (int j = 0; j < 16; ++j) acc[j] = 0.f;
    float ltot = 0.f;

    #pragma unroll
    for (int s = 0; s < 8; ++s)
        if (s < nseg) {
            const float wsc = __expf(ms[s] - M);
            ltot += wsc * ls[s];
            const ushort_t* Ob = reinterpret_cast<const ushort_t*>(
                Pbase + (size_t)(slot0 + s) * SLOT_BYTES) + row * 64 + d0;
            uint4 u0 = *reinterpret_cast<const uint4*>(Ob);
            uint4 u1 = *reinterpret_cast<const uint4*>(Ob + 8);
            const uint_t* uu = reinterpret_cast<const uint_t*>(&u0);
            #pragma unroll
            for (int j = 0; j < 4; ++j) {
                acc[2*j+0] += wsc * bf2f(uu[j] & 0xffffu);
                acc[2*j+1] += wsc * bf2f(uu[j] >> 16);
            }
            const uint_t* uv = reinterpret_cast<const uint_t*>(&u1);
            #pragma unroll
            for (int j = 0; j < 4; ++j) {
                acc[8+2*j+0] += wsc * bf2f(uv[j] & 0xffffu);
                acc[8+2*j+1] += wsc * bf2f(uv[j] >> 16);
            }
        }

    const float inv = 1.0f / ltot;
    float* op = Out + ((size_t)(batch * NT) + qt * 64 + row) * DK + d0;
    #pragma unroll
    for (int j = 0; j < 16; ++j) op[j] = acc[j] * inv;
}

extern "C" void kernel_launch(void* const* d_in, const int* in_sizes, int n_in,
                              void* d_out, int out_size, void* d_ws, size_t ws_size,
                              hipStream_t stream) {
    const float* X  = (const float*)d_in[0];
    const float* Wq = (const float*)d_in[1];
    const float* bq = (const float*)d_in[2];
    const float* Wk = (const float*)d_in[3];
    const float* bk = (const float*)d_in[4];
    const float* Wv = (const float*)d_in[5];
    const float* bv = (const float*)d_in[6];
    float* Out = (float*)d_out;
    ushort_t* QKV = (ushort_t*)d_ws;                 // Q | K | V^T, each BT*DK bf16
    char* Pbase   = (char*)d_ws + QKV_BYTES;         // 1120 slots x 8704 B (~9.7 MB)
    ushort_t* WtP = (ushort_t*)d_out;                // fragment-packed W (384 KB),
                                                     // consumed by proj, overwritten by attn

    wt_prep_kernel<<<96, 256, 0, stream>>>(Wq, Wk, Wv, WtP);
    qkv_mfma_kernel<<<512, 512, 0, stream>>>(X, WtP, bq, bk, bv, QKV);
    attn_seg_kernel<<<576, 256, 0, stream>>>(QKV, Out, Pbase);
    attn_combine_kernel<<<224, 256, 0, stream>>>(Pbase, Out);
}

// Round 17
// 60.173 us; speedup vs baseline: 1.2727x; 1.2727x over previous
//
#include <hip/hip_runtime.h>
#include <math.h>

#define NB 8
#define NT 2048
#define NC 1024
#define DK 64
#define BT (NB*NT)

// ws layout: QKV bf16 (6,291,456 B) | attention partials (1120 slots x 8704 B)
#define QKV_BYTES  (3u * BT * DK * 2u)
#define SLOT_BYTES 8704u   // Obf[64][64] bf16 (8192) + m f32[64] (256) + l f32[64] (256)

typedef unsigned short ushort_t;
typedef unsigned int uint_t;
typedef __attribute__((ext_vector_type(8))) short short8;
typedef __attribute__((ext_vector_type(4))) float f32x4;

__device__ __forceinline__ float bf2f(uint_t u) {
    union { uint_t i; float f; } v;
    v.i = u << 16;
    return v.f;
}
__device__ __forceinline__ ushort_t f2bf(float f) {
    union { float f; uint_t i; } v; v.f = f;
    uint_t x = v.i;
    return (ushort_t)((x + 0x7fffu + ((x >> 16) & 1u)) >> 16);
}
__device__ __forceinline__ uint_t pack2bf(float lo, float hi) {
    return (uint_t)f2bf(lo) | ((uint_t)f2bf(hi) << 16);
}

// slot prefix within a batch for q-tile qt (qt>=4): sum of nseg over q'=4..qt-1,
// nseg(q') = q'/4 + 1.  140 slots per batch total.
__device__ __forceinline__ int seg_prefix(int qt) {
    const int a = qt >> 2;
    return 2 * a * (a + 1) - 4 + (qt & 3) * (a + 1);
}

// ---------------------------------------------------------------------------
// Kernel 0: W fragment-pack prep (r14 layout, unchanged): 384 KB in d_out.
// ---------------------------------------------------------------------------
__global__ __launch_bounds__(256) void wt_prep_kernel(
    const float* __restrict__ Wq, const float* __restrict__ Wk,
    const float* __restrict__ Wv, ushort_t* __restrict__ WtP)
{
    const int tid = blockIdx.x * 256 + threadIdx.x;   // 0..24575
    int idx = tid;
    const int lane = idx & 63;  idx >>= 6;
    const int j    = idx % 6;   idx /= 6;
    const int w    = idx & 3;   idx >>= 2;
    const int ks   = idx & 7;   idx >>= 3;
    const int grp  = idx & 1;

    const int col = lane & 15;
    const int g   = lane >> 4;
    const int tj  = j >> 1;
    const int c   = j & 1;
    const int ng  = 48 * w + 16 * tj + col;
    const int which = ng >> 6, ncol = ng & 63;
    const float* W = (which == 0) ? Wq : (which == 1) ? Wk : Wv;
    const int kb = grp * 512 + ks * 64 + 32 * c + 8 * g;

    ushort_t o[8];
    #pragma unroll
    for (int i = 0; i < 8; ++i) o[i] = f2bf(W[(size_t)(kb + i) * DK + ncol]);
    *reinterpret_cast<uint4*>(&WtP[(size_t)tid * 8]) = *reinterpret_cast<uint4*>(o);
}

// ---------------------------------------------------------------------------
// Kernel 1: QKV projection on MFMA — r17: r14 structure (LDS-staged X +
// packed W + in-block K-split) with M-tile 16 -> grid 1024 (4 blocks/CU,
// 2x the independent barrier-groups per CU; the r13 counters showed ~85%
// barrier-convoy stall at 2 blocks/CU).
// ---------------------------------------------------------------------------
__global__ __launch_bounds__(512) void qkv_mfma_kernel(
    const float* __restrict__ X, const ushort_t* __restrict__ WtP,
    const float* __restrict__ bq, const float* __restrict__ bk,
    const float* __restrict__ bv, ushort_t* __restrict__ QKV)
{
    __shared__ ushort_t Xs[2][2][16 * 72];   // [group][buf]  (9.2 KB)
    __shared__ float    Racc[16 * 196];      // group-1 partial (12.5 KB)
    __shared__ ushort_t VtL[64 * 24];        // V bounce (3 KB)

    const int t    = threadIdx.x;
    const int grp  = t >> 8;          // 0,1 : K-half
    const int tg   = t & 255;         // id within group
    const int w    = (t >> 6) & 3;    // col-wave within group
    const int lane = t & 63;
    const int g    = lane >> 4;
    const int col  = lane & 15;
    const int m0   = blockIdx.x * 16;
    const int kb   = grp * 512;

    const int xrow = tg >> 4;         // 0..15
    const int xc   = (tg & 15) * 4;   // 0..60

    float xf[4];
    short8 wA[6], wB[6];

    auto LOADX = [&](int k0) {
        float4 v = *reinterpret_cast<const float4*>(
            &X[(size_t)(m0 + xrow) * NC + kb + k0 + xc]);
        xf[0] = v.x; xf[1] = v.y; xf[2] = v.z; xf[3] = v.w;
    };
    // fragment-packed, fully coalesced: 6 x 1KB wave-loads
    auto LOADW = [&](int ks, short8* wn) {
        const ushort_t* base = WtP + ((size_t)((grp * 8 + ks) * 4 + w)) * (6 * 64 * 8);
        #pragma unroll
        for (int j = 0; j < 6; ++j)
            wn[j] = *reinterpret_cast<const short8*>(base + (j * 64 + lane) * 8);
    };
    auto WRITEX = [&](int b) {
        ushort_t xb[4];
        #pragma unroll
        for (int j = 0; j < 4; ++j) xb[j] = f2bf(xf[j]);
        *reinterpret_cast<uint2*>(&Xs[grp][b][xrow * 72 + xc]) =
            *reinterpret_cast<uint2*>(xb);
    };

    f32x4 acc[3];
    #pragma unroll
    for (int tj = 0; tj < 3; ++tj) acc[tj] = (f32x4){0.f, 0.f, 0.f, 0.f};

    auto COMPUTE = [&](int cur, short8* wc) {
        const ushort_t* XsB = Xs[grp][cur];
        #pragma unroll
        for (int c = 0; c < 2; ++c) {
            short8 af = *reinterpret_cast<const short8*>(
                &XsB[col * 72 + 32 * c + 8 * g]);
            #pragma unroll
            for (int tj = 0; tj < 3; ++tj)
                acc[tj] = __builtin_amdgcn_mfma_f32_16x16x32_bf16(
                    af, wc[tj * 2 + c], acc[tj], 0, 0, 0);
        }
    };

    LOADX(0);
    LOADW(0, wA);
    WRITEX(0);

    #pragma unroll
    for (int ks2 = 0; ks2 < 4; ++ks2) {
        {
            const int ks = 2 * ks2;
            if (ks < 7) { LOADX((ks + 1) * 64); LOADW(ks + 1, wB); }
            __syncthreads();
            COMPUTE(0, wA);
            if (ks < 7) WRITEX(1);
        }
        {
            const int ks = 2 * ks2 + 1;
            if (ks < 7) { LOADX((ks + 1) * 64); LOADW(ks + 1, wA); }
            __syncthreads();
            COMPUTE(1, wB);
            if (ks < 7) WRITEX(0);
        }
    }

    // ---- merge the two K-halves via LDS ----
    __syncthreads();
    if (grp == 1) {
        #pragma unroll
        for (int tj = 0; tj < 3; ++tj)
            #pragma unroll
            for (int r = 0; r < 4; ++r)
                Racc[(4 * g + r) * 196 + 48 * w + 16 * tj + col] = acc[tj][r];
    }
    __syncthreads();
    if (grp == 0) {
        #pragma unroll
        for (int tj = 0; tj < 3; ++tj)
            #pragma unroll
            for (int r = 0; r < 4; ++r)
                acc[tj][r] += Racc[(4 * g + r) * 196 + 48 * w + 16 * tj + col];

        // epilogue: Q/K scatter stores (+bias, Q pre-scaled); V into VtL
        #pragma unroll
        for (int tj = 0; tj < 3; ++tj) {
            const int ng    = 48 * w + 16 * tj + col;
            const int which = ng >> 6, ncol = ng & 63;
            const float* bp = (which == 0) ? bq : (which == 1) ? bk : bv;
            const float bb  = bp[ncol];
            if (which == 2) {
                #pragma unroll
                for (int r = 0; r < 4; ++r)
                    VtL[ncol * 24 + 4 * g + r] = f2bf(acc[tj][r] + bb);
            } else {
                const float qs = (which == 0) ? 0.125f : 1.0f;
                ushort_t* Y = QKV + (size_t)which * BT * DK;
                #pragma unroll
                for (int r = 0; r < 4; ++r) {
                    const int rowg = m0 + 4 * g + r;
                    Y[(size_t)rowg * DK + ncol] = f2bf((acc[tj][r] + bb) * qs);
                }
            }
        }
    }
    __syncthreads();
    {   // coalesced V^T store: 64 d-rows x 32B, 512 threads x 4B
        ushort_t* Vt = QKV + (size_t)2 * BT * DK;
        const int d  = t >> 3;
        const int sg = t & 7;
        uint_t v = *reinterpret_cast<const uint_t*>(&VtL[d * 24 + sg * 2]);
        *reinterpret_cast<uint_t*>(&Vt[(size_t)d * BT + m0 + sg * 2]) = v;
    }
}

// ---------------------------------------------------------------------------
// Kernel 2: causal flash attention — k-segment-resident, zero hot-loop
// barriers, 2-way q-tile ILP (round-11 structure, unchanged).
// ---------------------------------------------------------------------------
__global__ __launch_bounds__(256) void attn_seg_kernel(
    const ushort_t* __restrict__ QKV, float* __restrict__ Out,
    char* __restrict__ Pbase)
{
    const ushort_t* Qw = QKV;
    const ushort_t* Kw = QKV + (size_t)BT * DK;
    const ushort_t* Vw = QKV + (size_t)2 * BT * DK;   // [DK][BT]

    __shared__ ushort_t Ks[256 * 72];
    __shared__ ushort_t VtL[64 * 288];

    const int t     = threadIdx.x;
    const int w     = t >> 6;
    const int lane  = t & 63;
    const int g     = lane >> 4;
    const int col   = lane & 15;
    const int batch = blockIdx.x & 7;
    const int u     = blockIdx.x >> 3;   // 0..71

    int s;
    if      (u < 16) s = 0;
    else if (u < 30) s = 1;
    else if (u < 42) s = 2;
    else if (u < 52) s = 3;
    else if (u < 60) s = 4;
    else if (u < 66) s = 5;
    else if (u < 70) s = 6;
    else             s = 7;
    const int off2 = 16 * s - s * (s - 1);
    const int qt0  = 4 * s + 2 * (u - off2);
    const int kbase = 256 * s;
    const int diag0 = qt0 - 4 * s;
    const int ntile = min(4, diag0 + 2);

    {
        const int sr = t >> 2;
        const int ss = t & 3;
        for (int i = 0; i < ntile; ++i) {
            const int krow = 64 * i + sr;
            const size_t gk = ((size_t)(batch * NT) + kbase + krow) * DK + ss * 16;
            const uint4* kp = reinterpret_cast<const uint4*>(Kw + gk);
            *reinterpret_cast<uint4*>(&Ks[krow * 72 + ss * 16])     = kp[0];
            *reinterpret_cast<uint4*>(&Ks[krow * 72 + ss * 16 + 8]) = kp[1];
            const size_t gv = (size_t)sr * BT + (batch * NT + kbase + 64 * i) + ss * 16;
            const uint4* vp = reinterpret_cast<const uint4*>(Vw + gv);
            *reinterpret_cast<uint4*>(&VtL[sr * 288 + 72 * i + ss * 16])     = vp[0];
            *reinterpret_cast<uint4*>(&VtL[sr * 288 + 72 * i + ss * 16 + 8]) = vp[1];
        }
    }
    __syncthreads();   // the ONLY barrier

    const int qrow0 = qt0 * 64 + 16 * w + col;
    const int qrow1 = qrow0 + 64;

    short8 q0a, q0b, q1a, q1b;
    {
        const ushort_t* Qr0 = Qw + ((size_t)(batch * NT) + qrow0) * DK;
        q0a = *reinterpret_cast<const short8*>(Qr0 + 8 * g);
        q0b = *reinterpret_cast<const short8*>(Qr0 + 32 + 8 * g);
        const ushort_t* Qr1 = Qw + ((size_t)(batch * NT) + qrow1) * DK;
        q1a = *reinterpret_cast<const short8*>(Qr1 + 8 * g);
        q1b = *reinterpret_cast<const short8*>(Qr1 + 32 + 8 * g);
    }

    f32x4 Oa0[4], Oa1[4];
    #pragma unroll
    for (int dt = 0; dt < 4; ++dt) {
        Oa0[dt] = (f32x4){0.f, 0.f, 0.f, 0.f};
        Oa1[dt] = (f32x4){0.f, 0.f, 0.f, 0.f};
    }
    float m0 = -INFINITY, l0 = 0.0f;
    float m1 = -INFINITY, l1 = 0.0f;

    for (int ktl = 0; ktl < ntile; ++ktl) {
        f32x4 sa0[4], sa1[4];
        #pragma unroll
        for (int tj = 0; tj < 4; ++tj) {
            sa0[tj] = (f32x4){0.f, 0.f, 0.f, 0.f};
            sa1[tj] = (f32x4){0.f, 0.f, 0.f, 0.f};
        }
        __builtin_amdgcn_s_setprio(1);
        #pragma unroll
        for (int tj = 0; tj < 4; ++tj) {
            const ushort_t* kb = &Ks[(64 * ktl + col + 16 * tj) * 72 + 8 * g];
            short8 kf0 = *reinterpret_cast<const short8*>(kb);
            short8 kf1 = *reinterpret_cast<const short8*>(kb + 32);
            sa0[tj] = __builtin_amdgcn_mfma_f32_16x16x32_bf16(kf0, q0a, sa0[tj], 0, 0, 0);
            sa0[tj] = __builtin_amdgcn_mfma_f32_16x16x32_bf16(kf1, q0b, sa0[tj], 0, 0, 0);
            sa1[tj] = __builtin_amdgcn_mfma_f32_16x16x32_bf16(kf0, q1a, sa1[tj], 0, 0, 0);
            sa1[tj] = __builtin_amdgcn_mfma_f32_16x16x32_bf16(kf1, q1b, sa1[tj], 0, 0, 0);
        }
        __builtin_amdgcn_s_setprio(0);

        const int s0 = kbase + 64 * ktl;
        if (ktl >= diag0) {
            #pragma unroll
            for (int tj = 0; tj < 4; ++tj)
                #pragma unroll
                for (int r = 0; r < 4; ++r)
                    if (s0 + 16 * tj + 4 * g + r > qrow0) sa0[tj][r] = -INFINITY;
        }
        if (ktl >= diag0 + 1) {
            #pragma unroll
            for (int tj = 0; tj < 4; ++tj)
                #pragma unroll
                for (int r = 0; r < 4; ++r)
                    if (s0 + 16 * tj + 4 * g + r > qrow1) sa1[tj][r] = -INFINITY;
        }

        float vx0 = sa0[0][0], vx1 = sa1[0][0];
        #pragma unroll
        for (int tj = 0; tj < 4; ++tj)
            #pragma unroll
            for (int r = 0; r < 4; ++r) {
                vx0 = fmaxf(vx0, sa0[tj][r]);
                vx1 = fmaxf(vx1, sa1[tj][r]);
            }
        vx0 = fmaxf(vx0, __shfl_xor(vx0, 16, 64));
        vx1 = fmaxf(vx1, __shfl_xor(vx1, 16, 64));
        vx0 = fmaxf(vx0, __shfl_xor(vx0, 32, 64));
        vx1 = fmaxf(vx1, __shfl_xor(vx1, 32, 64));

        const float mn0 = fmaxf(m0, vx0);
        const float mn1 = fmaxf(m1, vx1);
        const float sc0 = __expf(m0 - mn0);
        const float sc1 = __expf(m1 - mn1);
        m0 = mn0; m1 = mn1;

        float lt0 = 0.f, lt1 = 0.f;
        #pragma unroll
        for (int tj = 0; tj < 4; ++tj)
            #pragma unroll
            for (int r = 0; r < 4; ++r) {
                sa0[tj][r] = __expf(sa0[tj][r] - mn0);
                sa1[tj][r] = __expf(sa1[tj][r] - mn1);
                lt0 += sa0[tj][r];
                lt1 += sa1[tj][r];
            }
        lt0 += __shfl_xor(lt0, 16, 64);
        lt1 += __shfl_xor(lt1, 16, 64);
        lt0 += __shfl_xor(lt0, 32, 64);
        lt1 += __shfl_xor(lt1, 32, 64);
        l0 = l0 * sc0 + lt0;
        l1 = l1 * sc1 + lt1;

        float sco0[4], sco1[4];
        #pragma unroll
        for (int r = 0; r < 4; ++r) {
            sco0[r] = __shfl(sc0, 20 * g + r, 64);
            sco1[r] = __shfl(sc1, 20 * g + r, 64);
        }
        #pragma unroll
        for (int dt = 0; dt < 4; ++dt)
            #pragma unroll
            for (int r = 0; r < 4; ++r) {
                Oa0[dt][r] *= sco0[r];
                Oa1[dt][r] *= sco1[r];
            }

        uint_t pk00[4], pk01[4], pk10[4], pk11[4];
        #pragma unroll
        for (int tj = 0; tj < 4; ++tj) {
            pk00[tj] = pack2bf(sa0[tj][0], sa0[tj][1]);
            pk01[tj] = pack2bf(sa0[tj][2], sa0[tj][3]);
            pk10[tj] = pack2bf(sa1[tj][0], sa1[tj][1]);
            pk11[tj] = pack2bf(sa1[tj][2], sa1[tj][3]);
        }
        const int sA = col + 32 * (g & 1);
        const int sB = sA + 16;
        const bool hi = (g >= 2);

        #pragma unroll
        for (int c = 0; c < 2; ++c) {
            uint_t a0 = __shfl(pk00[2*c], sA, 64), b0 = __shfl(pk00[2*c+1], sA, 64);
            uint_t a1 = __shfl(pk01[2*c], sA, 64), b1 = __shfl(pk01[2*c+1], sA, 64);
            uint_t a2 = __shfl(pk00[2*c], sB, 64), b2 = __shfl(pk00[2*c+1], sB, 64);
            uint_t a3 = __shfl(pk01[2*c], sB, 64), b3 = __shfl(pk01[2*c+1], sB, 64);
            uint_t c0 = __shfl(pk10[2*c], sA, 64), d0 = __shfl(pk10[2*c+1], sA, 64);
            uint_t c1 = __shfl(pk11[2*c], sA, 64), d1 = __shfl(pk11[2*c+1], sA, 64);
            uint_t c2 = __shfl(pk10[2*c], sB, 64), d2 = __shfl(pk10[2*c+1], sB, 64);
            uint_t c3 = __shfl(pk11[2*c], sB, 64), d3 = __shfl(pk11[2*c+1], sB, 64);
            uint_t pa0[4], pa1[4];
            pa0[0] = hi ? b0 : a0;
            pa0[1] = hi ? b1 : a1;
            pa0[2] = hi ? b2 : a2;
            pa0[3] = hi ? b3 : a3;
            pa1[0] = hi ? d0 : c0;
            pa1[1] = hi ? d1 : c1;
            pa1[2] = hi ? d2 : c2;
            pa1[3] = hi ? d3 : c3;
            short8 paf0 = *reinterpret_cast<const short8*>(pa0);
            short8 paf1 = *reinterpret_cast<const short8*>(pa1);
            __builtin_amdgcn_s_setprio(1);
            #pragma unroll
            for (int dt = 0; dt < 4; ++dt) {
                short8 vf = *reinterpret_cast<const short8*>(
                    &VtL[(col + 16 * dt) * 288 + 72 * ktl + 32 * c + 8 * g]);
                Oa0[dt] = __builtin_amdgcn_mfma_f32_16x16x32_bf16(paf0, vf, Oa0[dt], 0, 0, 0);
                Oa1[dt] = __builtin_amdgcn_mfma_f32_16x16x32_bf16(paf1, vf, Oa1[dt], 0, 0, 0);
            }
            __builtin_amdgcn_s_setprio(0);
        }
    }

    // ---- epilogue, per q-tile ----
    #pragma unroll
    for (int iq = 0; iq < 2; ++iq) {
        const int qt = qt0 + iq;
        const float mm = iq ? m1 : m0;
        const float ll = iq ? l1 : l0;
        const f32x4* Oa = iq ? Oa1 : Oa0;

        float lr[4];
        #pragma unroll
        for (int r = 0; r < 4; ++r) lr[r] = __shfl(ll, 20 * g + r, 64);

        if (qt < 4) {
            #pragma unroll
            for (int r = 0; r < 4; ++r) {
                const float inv = 1.0f / lr[r];
                const int row = qt * 64 + 16 * w + 4 * g + r;
                float* op = Out + ((size_t)(batch * NT) + row) * DK + col;
                #pragma unroll
                for (int dt = 0; dt < 4; ++dt) op[16 * dt] = Oa[dt][r] * inv;
            }
        } else {
            float mr[4];
            #pragma unroll
            for (int r = 0; r < 4; ++r) mr[r] = __shfl(mm, 20 * g + r, 64);
            const int slot = batch * 140 + seg_prefix(qt) + s;
            char* sp = Pbase + (size_t)slot * SLOT_BYTES;
            ushort_t* Ob  = reinterpret_cast<ushort_t*>(sp);
            float*    Pm  = reinterpret_cast<float*>(sp + 8192);
            float*    Plv = reinterpret_cast<float*>(sp + 8448);
            #pragma unroll
            for (int r = 0; r < 4; ++r) {
                const int rloc = 16 * w + 4 * g + r;
                #pragma unroll
                for (int dt = 0; dt < 4; ++dt)
                    Ob[rloc * 64 + 16 * dt + col] = f2bf(Oa[dt][r]);
                if (col == 0) { Pm[rloc] = mr[r]; Plv[rloc] = lr[r]; }
            }
        }
    }
}

// ---------------------------------------------------------------------------
// Kernel 3: combine partial segments (unchanged).
// ---------------------------------------------------------------------------
__global__ __launch_bounds__(256) void attn_combine_kernel(
    const char* __restrict__ Pbase, float* __restrict__ Out)
{
    const int bid   = blockIdx.x;       // 0..223
    const int batch = bid / 28;
    const int qt    = 4 + bid % 28;
    const int nseg  = (qt >> 2) + 1;    // 2..8
    const int slot0 = batch * 140 + seg_prefix(qt);

    const int t   = threadIdx.x;
    const int row = t >> 2;
    const int d0  = (t & 3) * 16;

    float ms[8], ls[8];
    float M = -INFINITY;
    #pragma unroll
    for (int s = 0; s < 8; ++s)
        if (s < nseg) {
            const char* sp = Pbase + (size_t)(slot0 + s) * SLOT_BYTES;
            ms[s] = reinterpret_cast<const float*>(sp + 8192)[row];
            ls[s] = reinterpret_cast<const float*>(sp + 8448)[row];
            M = fmaxf(M, ms[s]);
        }

    float acc[16];
    #pragma unroll
    for (int j = 0; j < 16; ++j) acc[j] = 0.f;
    float ltot = 0.f;

    #pragma unroll
    for (int s = 0; s < 8; ++s)
        if (s < nseg) {
            const float wsc = __expf(ms[s] - M);
            ltot += wsc * ls[s];
            const ushort_t* Ob = reinterpret_cast<const ushort_t*>(
                Pbase + (size_t)(slot0 + s) * SLOT_BYTES) + row * 64 + d0;
            uint4 u0 = *reinterpret_cast<const uint4*>(Ob);
            uint4 u1 = *reinterpret_cast<const uint4*>(Ob + 8);
            const uint_t* uu = reinterpret_cast<const uint_t*>(&u0);
            #pragma unroll
            for (int j = 0; j < 4; ++j) {
                acc[2*j+0] += wsc * bf2f(uu[j] & 0xffffu);
                acc[2*j+1] += wsc * bf2f(uu[j] >> 16);
            }
            const uint_t* uv = reinterpret_cast<const uint_t*>(&u1);
            #pragma unroll
            for (int j = 0; j < 4; ++j) {
                acc[8+2*j+0] += wsc * bf2f(uv[j] & 0xffffu);
                acc[8+2*j+1] += wsc * bf2f(uv[j] >> 16);
            }
        }

    const float inv = 1.0f / ltot;
    float* op = Out + ((size_t)(batch * NT) + qt * 64 + row) * DK + d0;
    #pragma unroll
    for (int j = 0; j < 16; ++j) op[j] = acc[j] * inv;
}

extern "C" void kernel_launch(void* const* d_in, const int* in_sizes, int n_in,
                              void* d_out, int out_size, void* d_ws, size_t ws_size,
                              hipStream_t stream) {
    const float* X  = (const float*)d_in[0];
    const float* Wq = (const float*)d_in[1];
    const float* bq = (const float*)d_in[2];
    const float* Wk = (const float*)d_in[3];
    const float* bk = (const float*)d_in[4];
    const float* Wv = (const float*)d_in[5];
    const float* bv = (const float*)d_in[6];
    float* Out = (float*)d_out;
    ushort_t* QKV = (ushort_t*)d_ws;                 // Q | K | V^T, each BT*DK bf16
    char* Pbase   = (char*)d_ws + QKV_BYTES;         // 1120 slots x 8704 B (~9.7 MB)
    ushort_t* WtP = (ushort_t*)d_out;                // fragment-packed W (384 KB),
                                                     // consumed by proj, overwritten by attn

    wt_prep_kernel<<<96, 256, 0, stream>>>(Wq, Wk, Wv, WtP);
    qkv_mfma_kernel<<<1024, 512, 0, stream>>>(X, WtP, bq, bk, bv, QKV);
    attn_seg_kernel<<<576, 256, 0, stream>>>(QKV, Out, Pbase);
    attn_combine_kernel<<<224, 256, 0, stream>>>(Pbase, Out);
}

// Round 18
// 54.108 us; speedup vs baseline: 1.4154x; 1.1121x over previous
//
#include <hip/hip_runtime.h>
#include <math.h>

#define NB 8
#define NT 2048
#define NC 1024
#define DK 64
#define BT (NB*NT)

// ws layout: QKV bf16 (6,291,456 B) | attention partials (1120 slots x 8704 B)
#define QKV_BYTES  (3u * BT * DK * 2u)
#define SLOT_BYTES 8704u   // Obf[64][64] bf16 (8192) + m f32[64] (256) + l f32[64] (256)

typedef unsigned short ushort_t;
typedef unsigned int uint_t;
typedef __attribute__((ext_vector_type(8))) short short8;
typedef __attribute__((ext_vector_type(4))) float f32x4;

__device__ __forceinline__ float bf2f(uint_t u) {
    union { uint_t i; float f; } v;
    v.i = u << 16;
    return v.f;
}
__device__ __forceinline__ ushort_t f2bf(float f) {
    union { float f; uint_t i; } v; v.f = f;
    uint_t x = v.i;
    return (ushort_t)((x + 0x7fffu + ((x >> 16) & 1u)) >> 16);
}
__device__ __forceinline__ uint_t pack2bf(float lo, float hi) {
    return (uint_t)f2bf(lo) | ((uint_t)f2bf(hi) << 16);
}

// slot prefix within a batch for q-tile qt (qt>=4): sum of nseg over q'=4..qt-1,
// nseg(q') = q'/4 + 1.  140 slots per batch total.
__device__ __forceinline__ int seg_prefix(int qt) {
    const int a = qt >> 2;
    return 2 * a * (a + 1) - 4 + (qt & 3) * (a + 1);
}

// ---------------------------------------------------------------------------
// Kernel 0: W fragment-pack prep (r14 layout, unchanged): 384 KB in d_out.
// ---------------------------------------------------------------------------
__global__ __launch_bounds__(256) void wt_prep_kernel(
    const float* __restrict__ Wq, const float* __restrict__ Wk,
    const float* __restrict__ Wv, ushort_t* __restrict__ WtP)
{
    const int tid = blockIdx.x * 256 + threadIdx.x;   // 0..24575
    int idx = tid;
    const int lane = idx & 63;  idx >>= 6;
    const int j    = idx % 6;   idx /= 6;
    const int w    = idx & 3;   idx >>= 2;
    const int ks   = idx & 7;   idx >>= 3;
    const int grp  = idx & 1;

    const int col = lane & 15;
    const int g   = lane >> 4;
    const int tj  = j >> 1;
    const int c   = j & 1;
    const int ng  = 48 * w + 16 * tj + col;
    const int which = ng >> 6, ncol = ng & 63;
    const float* W = (which == 0) ? Wq : (which == 1) ? Wk : Wv;
    const int kb = grp * 512 + ks * 64 + 32 * c + 8 * g;

    ushort_t o[8];
    #pragma unroll
    for (int i = 0; i < 8; ++i) o[i] = f2bf(W[(size_t)(kb + i) * DK + ncol]);
    *reinterpret_cast<uint4*>(&WtP[(size_t)tid * 8]) = *reinterpret_cast<uint4*>(o);
}

// ---------------------------------------------------------------------------
// Kernel 1: QKV projection on MFMA — r18: M-tile 64, grid 256 (1 block/CU).
// W L2 traffic halves vs r14 (196->98 MB) and each W fragment feeds 2x the
// MFMAs (r17's M16 regression confirmed the W-traffic model: time scales
// with grid x 384KB W reads).  LDS aliased: X-stage (36.8 KB) during loop,
// Racc(50.2 KB)+V-bounce(9.2 KB) in epilogue via union.
// ---------------------------------------------------------------------------
__global__ __launch_bounds__(512) void qkv_mfma_kernel(
    const float* __restrict__ X, const ushort_t* __restrict__ WtP,
    const float* __restrict__ bq, const float* __restrict__ bk,
    const float* __restrict__ bv, ushort_t* __restrict__ QKV)
{
    union SMemU {
        ushort_t xs[2][2][64 * 72];                       // loop phase
        struct { float racc[64 * 196]; ushort_t vtl[64 * 72]; } e;   // epilogue
    };
    __shared__ SMemU sm;

    const int t    = threadIdx.x;
    const int grp  = t >> 8;          // 0,1 : K-half
    const int tg   = t & 255;         // id within group
    const int w    = (t >> 6) & 3;    // col-wave within group
    const int lane = t & 63;
    const int g    = lane >> 4;
    const int col  = lane & 15;
    const int m0   = blockIdx.x * 64;
    const int kb   = grp * 512;

    const int xrow = tg >> 2;         // 0..63
    const int xc   = (tg & 3) * 16;   // 0,16,32,48

    float xf[16];
    short8 wA[6], wB[6];

    auto LOADX = [&](int k0) {
        const float4* xp = reinterpret_cast<const float4*>(
            &X[(size_t)(m0 + xrow) * NC + kb + k0 + xc]);
        #pragma unroll
        for (int j = 0; j < 4; ++j) {
            float4 v = xp[j];
            xf[4*j+0] = v.x; xf[4*j+1] = v.y; xf[4*j+2] = v.z; xf[4*j+3] = v.w;
        }
    };
    // fragment-packed, fully coalesced: 6 x 1KB wave-loads
    auto LOADW = [&](int ks, short8* wn) {
        const ushort_t* base = WtP + ((size_t)((grp * 8 + ks) * 4 + w)) * (6 * 64 * 8);
        #pragma unroll
        for (int j = 0; j < 6; ++j)
            wn[j] = *reinterpret_cast<const short8*>(base + (j * 64 + lane) * 8);
    };
    auto WRITEX = [&](int b) {
        ushort_t xb[16];
        #pragma unroll
        for (int j = 0; j < 16; ++j) xb[j] = f2bf(xf[j]);
        *reinterpret_cast<uint4*>(&sm.xs[grp][b][xrow * 72 + xc])     =
            reinterpret_cast<uint4*>(xb)[0];
        *reinterpret_cast<uint4*>(&sm.xs[grp][b][xrow * 72 + xc + 8]) =
            reinterpret_cast<uint4*>(xb)[1];
    };

    f32x4 acc[4][3];
    #pragma unroll
    for (int ri = 0; ri < 4; ++ri)
        #pragma unroll
        for (int tj = 0; tj < 3; ++tj) acc[ri][tj] = (f32x4){0.f, 0.f, 0.f, 0.f};

    auto COMPUTE = [&](int cur, short8* wc) {
        const ushort_t* XsB = sm.xs[grp][cur];
        #pragma unroll
        for (int c = 0; c < 2; ++c) {
            short8 af[4];
            #pragma unroll
            for (int ri = 0; ri < 4; ++ri)
                af[ri] = *reinterpret_cast<const short8*>(
                    &XsB[(16 * ri + col) * 72 + 32 * c + 8 * g]);
            #pragma unroll
            for (int ri = 0; ri < 4; ++ri)
                #pragma unroll
                for (int tj = 0; tj < 3; ++tj)
                    acc[ri][tj] = __builtin_amdgcn_mfma_f32_16x16x32_bf16(
                        af[ri], wc[tj * 2 + c], acc[ri][tj], 0, 0, 0);
        }
    };

    LOADX(0);
    LOADW(0, wA);
    WRITEX(0);

    #pragma unroll
    for (int ks2 = 0; ks2 < 4; ++ks2) {
        {
            const int ks = 2 * ks2;
            if (ks < 7) { LOADX((ks + 1) * 64); LOADW(ks + 1, wB); }
            __syncthreads();
            COMPUTE(0, wA);
            if (ks < 7) WRITEX(1);
        }
        {
            const int ks = 2 * ks2 + 1;
            if (ks < 7) { LOADX((ks + 1) * 64); LOADW(ks + 1, wA); }
            __syncthreads();
            COMPUTE(1, wB);
            if (ks < 7) WRITEX(0);
        }
    }

    // ---- merge the two K-halves via LDS (Xs dead; alias Racc) ----
    __syncthreads();
    if (grp == 1) {
        #pragma unroll
        for (int ri = 0; ri < 4; ++ri)
            #pragma unroll
            for (int tj = 0; tj < 3; ++tj)
                #pragma unroll
                for (int r = 0; r < 4; ++r)
                    sm.e.racc[(16 * ri + 4 * g + r) * 196 + 48 * w + 16 * tj + col] =
                        acc[ri][tj][r];
    }
    __syncthreads();
    if (grp == 0) {
        #pragma unroll
        for (int ri = 0; ri < 4; ++ri)
            #pragma unroll
            for (int tj = 0; tj < 3; ++tj)
                #pragma unroll
                for (int r = 0; r < 4; ++r)
                    acc[ri][tj][r] +=
                        sm.e.racc[(16 * ri + 4 * g + r) * 196 + 48 * w + 16 * tj + col];

        // V (+bias) into the bounce buffer (disjoint from racc)
        #pragma unroll
        for (int tj = 0; tj < 3; ++tj) {
            const int ng    = 48 * w + 16 * tj + col;
            const int which = ng >> 6, ncol = ng & 63;
            if (which == 2) {
                const float bb = bv[ncol];
                #pragma unroll
                for (int ri = 0; ri < 4; ++ri)
                    #pragma unroll
                    for (int r = 0; r < 4; ++r)
                        sm.e.vtl[ncol * 72 + 16 * ri + 4 * g + r] =
                            f2bf(acc[ri][tj][r] + bb);
            }
        }
    }

    // ---- fully-coalesced Q/K epilogue via OutL (aliases racc) ----
    ushort_t* OutL = reinterpret_cast<ushort_t*>(sm.e.racc);

    #pragma unroll
    for (int pass = 0; pass < 2; ++pass) {   // 0: Q, 1: K
        __syncthreads();
        if (grp == 0) {
            #pragma unroll
            for (int tj = 0; tj < 3; ++tj) {
                const int ng    = 48 * w + 16 * tj + col;
                const int which = ng >> 6, ncol = ng & 63;
                if (which == pass) {
                    const float bb = (pass == 0) ? bq[ncol] : bk[ncol];
                    const float qs = (pass == 0) ? 0.125f : 1.0f;
                    #pragma unroll
                    for (int ri = 0; ri < 4; ++ri)
                        #pragma unroll
                        for (int r = 0; r < 4; ++r)
                            OutL[(16 * ri + 4 * g + r) * 72 + ncol] =
                                f2bf((acc[ri][tj][r] + bb) * qs);
                }
            }
        }
        __syncthreads();
        {   // coalesced copy-out: 64 rows x 128B, 512 threads x 16B
            ushort_t* Y = QKV + (size_t)pass * BT * DK;
            const int row = t >> 3;
            const int c8  = (t & 7) * 8;
            uint4 v = *reinterpret_cast<const uint4*>(&OutL[row * 72 + c8]);
            *reinterpret_cast<uint4*>(&Y[(size_t)(m0 + row) * DK + c8]) = v;
        }
    }

    __syncthreads();
    {   // coalesced V^T store: 64 d-rows x 128B, 512 threads x 16B
        ushort_t* Vt = QKV + (size_t)2 * BT * DK;
        const int d  = t >> 3;
        const int sg = t & 7;
        uint4 v = *reinterpret_cast<const uint4*>(&sm.e.vtl[d * 72 + sg * 8]);
        *reinterpret_cast<uint4*>(&Vt[(size_t)d * BT + m0 + sg * 8]) = v;
    }
}

// ---------------------------------------------------------------------------
// Kernel 2: causal flash attention — k-segment-resident, zero hot-loop
// barriers, 2-way q-tile ILP (round-11 structure, unchanged).
// ---------------------------------------------------------------------------
__global__ __launch_bounds__(256) void attn_seg_kernel(
    const ushort_t* __restrict__ QKV, float* __restrict__ Out,
    char* __restrict__ Pbase)
{
    const ushort_t* Qw = QKV;
    const ushort_t* Kw = QKV + (size_t)BT * DK;
    const ushort_t* Vw = QKV + (size_t)2 * BT * DK;   // [DK][BT]

    __shared__ ushort_t Ks[256 * 72];
    __shared__ ushort_t VtL[64 * 288];

    const int t     = threadIdx.x;
    const int w     = t >> 6;
    const int lane  = t & 63;
    const int g     = lane >> 4;
    const int col   = lane & 15;
    const int batch = blockIdx.x & 7;
    const int u     = blockIdx.x >> 3;   // 0..71

    int s;
    if      (u < 16) s = 0;
    else if (u < 30) s = 1;
    else if (u < 42) s = 2;
    else if (u < 52) s = 3;
    else if (u < 60) s = 4;
    else if (u < 66) s = 5;
    else if (u < 70) s = 6;
    else             s = 7;
    const int off2 = 16 * s - s * (s - 1);
    const int qt0  = 4 * s + 2 * (u - off2);
    const int kbase = 256 * s;
    const int diag0 = qt0 - 4 * s;
    const int ntile = min(4, diag0 + 2);

    {
        const int sr = t >> 2;
        const int ss = t & 3;
        for (int i = 0; i < ntile; ++i) {
            const int krow = 64 * i + sr;
            const size_t gk = ((size_t)(batch * NT) + kbase + krow) * DK + ss * 16;
            const uint4* kp = reinterpret_cast<const uint4*>(Kw + gk);
            *reinterpret_cast<uint4*>(&Ks[krow * 72 + ss * 16])     = kp[0];
            *reinterpret_cast<uint4*>(&Ks[krow * 72 + ss * 16 + 8]) = kp[1];
            const size_t gv = (size_t)sr * BT + (batch * NT + kbase + 64 * i) + ss * 16;
            const uint4* vp = reinterpret_cast<const uint4*>(Vw + gv);
            *reinterpret_cast<uint4*>(&VtL[sr * 288 + 72 * i + ss * 16])     = vp[0];
            *reinterpret_cast<uint4*>(&VtL[sr * 288 + 72 * i + ss * 16 + 8]) = vp[1];
        }
    }
    __syncthreads();   // the ONLY barrier

    const int qrow0 = qt0 * 64 + 16 * w + col;
    const int qrow1 = qrow0 + 64;

    short8 q0a, q0b, q1a, q1b;
    {
        const ushort_t* Qr0 = Qw + ((size_t)(batch * NT) + qrow0) * DK;
        q0a = *reinterpret_cast<const short8*>(Qr0 + 8 * g);
        q0b = *reinterpret_cast<const short8*>(Qr0 + 32 + 8 * g);
        const ushort_t* Qr1 = Qw + ((size_t)(batch * NT) + qrow1) * DK;
        q1a = *reinterpret_cast<const short8*>(Qr1 + 8 * g);
        q1b = *reinterpret_cast<const short8*>(Qr1 + 32 + 8 * g);
    }

    f32x4 Oa0[4], Oa1[4];
    #pragma unroll
    for (int dt = 0; dt < 4; ++dt) {
        Oa0[dt] = (f32x4){0.f, 0.f, 0.f, 0.f};
        Oa1[dt] = (f32x4){0.f, 0.f, 0.f, 0.f};
    }
    float m0 = -INFINITY, l0 = 0.0f;
    float m1 = -INFINITY, l1 = 0.0f;

    for (int ktl = 0; ktl < ntile; ++ktl) {
        f32x4 sa0[4], sa1[4];
        #pragma unroll
        for (int tj = 0; tj < 4; ++tj) {
            sa0[tj] = (f32x4){0.f, 0.f, 0.f, 0.f};
            sa1[tj] = (f32x4){0.f, 0.f, 0.f, 0.f};
        }
        __builtin_amdgcn_s_setprio(1);
        #pragma unroll
        for (int tj = 0; tj < 4; ++tj) {
            const ushort_t* kb = &Ks[(64 * ktl + col + 16 * tj) * 72 + 8 * g];
            short8 kf0 = *reinterpret_cast<const short8*>(kb);
            short8 kf1 = *reinterpret_cast<const short8*>(kb + 32);
            sa0[tj] = __builtin_amdgcn_mfma_f32_16x16x32_bf16(kf0, q0a, sa0[tj], 0, 0, 0);
            sa0[tj] = __builtin_amdgcn_mfma_f32_16x16x32_bf16(kf1, q0b, sa0[tj], 0, 0, 0);
            sa1[tj] = __builtin_amdgcn_mfma_f32_16x16x32_bf16(kf0, q1a, sa1[tj], 0, 0, 0);
            sa1[tj] = __builtin_amdgcn_mfma_f32_16x16x32_bf16(kf1, q1b, sa1[tj], 0, 0, 0);
        }
        __builtin_amdgcn_s_setprio(0);

        const int s0 = kbase + 64 * ktl;
        if (ktl >= diag0) {
            #pragma unroll
            for (int tj = 0; tj < 4; ++tj)
                #pragma unroll
                for (int r = 0; r < 4; ++r)
                    if (s0 + 16 * tj + 4 * g + r > qrow0) sa0[tj][r] = -INFINITY;
        }
        if (ktl >= diag0 + 1) {
            #pragma unroll
            for (int tj = 0; tj < 4; ++tj)
                #pragma unroll
                for (int r = 0; r < 4; ++r)
                    if (s0 + 16 * tj + 4 * g + r > qrow1) sa1[tj][r] = -INFINITY;
        }

        float vx0 = sa0[0][0], vx1 = sa1[0][0];
        #pragma unroll
        for (int tj = 0; tj < 4; ++tj)
            #pragma unroll
            for (int r = 0; r < 4; ++r) {
                vx0 = fmaxf(vx0, sa0[tj][r]);
                vx1 = fmaxf(vx1, sa1[tj][r]);
            }
        vx0 = fmaxf(vx0, __shfl_xor(vx0, 16, 64));
        vx1 = fmaxf(vx1, __shfl_xor(vx1, 16, 64));
        vx0 = fmaxf(vx0, __shfl_xor(vx0, 32, 64));
        vx1 = fmaxf(vx1, __shfl_xor(vx1, 32, 64));

        const float mn0 = fmaxf(m0, vx0);
        const float mn1 = fmaxf(m1, vx1);
        const float sc0 = __expf(m0 - mn0);
        const float sc1 = __expf(m1 - mn1);
        m0 = mn0; m1 = mn1;

        float lt0 = 0.f, lt1 = 0.f;
        #pragma unroll
        for (int tj = 0; tj < 4; ++tj)
            #pragma unroll
            for (int r = 0; r < 4; ++r) {
                sa0[tj][r] = __expf(sa0[tj][r] - mn0);
                sa1[tj][r] = __expf(sa1[tj][r] - mn1);
                lt0 += sa0[tj][r];
                lt1 += sa1[tj][r];
            }
        lt0 += __shfl_xor(lt0, 16, 64);
        lt1 += __shfl_xor(lt1, 16, 64);
        lt0 += __shfl_xor(lt0, 32, 64);
        lt1 += __shfl_xor(lt1, 32, 64);
        l0 = l0 * sc0 + lt0;
        l1 = l1 * sc1 + lt1;

        float sco0[4], sco1[4];
        #pragma unroll
        for (int r = 0; r < 4; ++r) {
            sco0[r] = __shfl(sc0, 20 * g + r, 64);
            sco1[r] = __shfl(sc1, 20 * g + r, 64);
        }
        #pragma unroll
        for (int dt = 0; dt < 4; ++dt)
            #pragma unroll
            for (int r = 0; r < 4; ++r) {
                Oa0[dt][r] *= sco0[r];
                Oa1[dt][r] *= sco1[r];
            }

        uint_t pk00[4], pk01[4], pk10[4], pk11[4];
        #pragma unroll
        for (int tj = 0; tj < 4; ++tj) {
            pk00[tj] = pack2bf(sa0[tj][0], sa0[tj][1]);
            pk01[tj] = pack2bf(sa0[tj][2], sa0[tj][3]);
            pk10[tj] = pack2bf(sa1[tj][0], sa1[tj][1]);
            pk11[tj] = pack2bf(sa1[tj][2], sa1[tj][3]);
        }
        const int sA = col + 32 * (g & 1);
        const int sB = sA + 16;
        const bool hi = (g >= 2);

        #pragma unroll
        for (int c = 0; c < 2; ++c) {
            uint_t a0 = __shfl(pk00[2*c], sA, 64), b0 = __shfl(pk00[2*c+1], sA, 64);
            uint_t a1 = __shfl(pk01[2*c], sA, 64), b1 = __shfl(pk01[2*c+1], sA, 64);
            uint_t a2 = __shfl(pk00[2*c], sB, 64), b2 = __shfl(pk00[2*c+1], sB, 64);
            uint_t a3 = __shfl(pk01[2*c], sB, 64), b3 = __shfl(pk01[2*c+1], sB, 64);
            uint_t c0 = __shfl(pk10[2*c], sA, 64), d0 = __shfl(pk10[2*c+1], sA, 64);
            uint_t c1 = __shfl(pk11[2*c], sA, 64), d1 = __shfl(pk11[2*c+1], sA, 64);
            uint_t c2 = __shfl(pk10[2*c], sB, 64), d2 = __shfl(pk10[2*c+1], sB, 64);
            uint_t c3 = __shfl(pk11[2*c], sB, 64), d3 = __shfl(pk11[2*c+1], sB, 64);
            uint_t pa0[4], pa1[4];
            pa0[0] = hi ? b0 : a0;
            pa0[1] = hi ? b1 : a1;
            pa0[2] = hi ? b2 : a2;
            pa0[3] = hi ? b3 : a3;
            pa1[0] = hi ? d0 : c0;
            pa1[1] = hi ? d1 : c1;
            pa1[2] = hi ? d2 : c2;
            pa1[3] = hi ? d3 : c3;
            short8 paf0 = *reinterpret_cast<const short8*>(pa0);
            short8 paf1 = *reinterpret_cast<const short8*>(pa1);
            __builtin_amdgcn_s_setprio(1);
            #pragma unroll
            for (int dt = 0; dt < 4; ++dt) {
                short8 vf = *reinterpret_cast<const short8*>(
                    &VtL[(col + 16 * dt) * 288 + 72 * ktl + 32 * c + 8 * g]);
                Oa0[dt] = __builtin_amdgcn_mfma_f32_16x16x32_bf16(paf0, vf, Oa0[dt], 0, 0, 0);
                Oa1[dt] = __builtin_amdgcn_mfma_f32_16x16x32_bf16(paf1, vf, Oa1[dt], 0, 0, 0);
            }
            __builtin_amdgcn_s_setprio(0);
        }
    }

    // ---- epilogue, per q-tile ----
    #pragma unroll
    for (int iq = 0; iq < 2; ++iq) {
        const int qt = qt0 + iq;
        const float mm = iq ? m1 : m0;
        const float ll = iq ? l1 : l0;
        const f32x4* Oa = iq ? Oa1 : Oa0;

        float lr[4];
        #pragma unroll
        for (int r = 0; r < 4; ++r) lr[r] = __shfl(ll, 20 * g + r, 64);

        if (qt < 4) {
            #pragma unroll
            for (int r = 0; r < 4; ++r) {
                const float inv = 1.0f / lr[r];
                const int row = qt * 64 + 16 * w + 4 * g + r;
                float* op = Out + ((size_t)(batch * NT) + row) * DK + col;
                #pragma unroll
                for (int dt = 0; dt < 4; ++dt) op[16 * dt] = Oa[dt][r] * inv;
            }
        } else {
            float mr[4];
            #pragma unroll
            for (int r = 0; r < 4; ++r) mr[r] = __shfl(mm, 20 * g + r, 64);
            const int slot = batch * 140 + seg_prefix(qt) + s;
            char* sp = Pbase + (size_t)slot * SLOT_BYTES;
            ushort_t* Ob  = reinterpret_cast<ushort_t*>(sp);
            float*    Pm  = reinterpret_cast<float*>(sp + 8192);
            float*    Plv = reinterpret_cast<float*>(sp + 8448);
            #pragma unroll
            for (int r = 0; r < 4; ++r) {
                const int rloc = 16 * w + 4 * g + r;
                #pragma unroll
                for (int dt = 0; dt < 4; ++dt)
                    Ob[rloc * 64 + 16 * dt + col] = f2bf(Oa[dt][r]);
                if (col == 0) { Pm[rloc] = mr[r]; Plv[rloc] = lr[r]; }
            }
        }
    }
}

// ---------------------------------------------------------------------------
// Kernel 3: combine partial segments (unchanged).
// ---------------------------------------------------------------------------
__global__ __launch_bounds__(256) void attn_combine_kernel(
    const char* __restrict__ Pbase, float* __restrict__ Out)
{
    const int bid   = blockIdx.x;       // 0..223
    const int batch = bid / 28;
    const int qt    = 4 + bid % 28;
    const int nseg  = (qt >> 2) + 1;    // 2..8
    const int slot0 = batch * 140 + seg_prefix(qt);

    const int t   = threadIdx.x;
    const int row = t >> 2;
    const int d0  = (t & 3) * 16;

    float ms[8], ls[8];
    float M = -INFINITY;
    #pragma unroll
    for (int s = 0; s < 8; ++s)
        if (s < nseg) {
            const char* sp = Pbase + (size_t)(slot0 + s) * SLOT_BYTES;
            ms[s] = reinterpret_cast<const float*>(sp + 8192)[row];
            ls[s] = reinterpret_cast<const float*>(sp + 8448)[row];
            M = fmaxf(M, ms[s]);
        }

    float acc[16];
    #pragma unroll
    for (int j = 0; j < 16; ++j) acc[j] = 0.f;
    float ltot = 0.f;

    #pragma unroll
    for (int s = 0; s < 8; ++s)
        if (s < nseg) {
            const float wsc = __expf(ms[s] - M);
            ltot += wsc * ls[s];
            const ushort_t* Ob = reinterpret_cast<const ushort_t*>(
                Pbase + (size_t)(slot0 + s) * SLOT_BYTES) + row * 64 + d0;
            uint4 u0 = *reinterpret_cast<const uint4*>(Ob);
            uint4 u1 = *reinterpret_cast<const uint4*>(Ob + 8);
            const uint_t* uu = reinterpret_cast<const uint_t*>(&u0);
            #pragma unroll
            for (int j = 0; j < 4; ++j) {
                acc[2*j+0] += wsc * bf2f(uu[j] & 0xffffu);
                acc[2*j+1] += wsc * bf2f(uu[j] >> 16);
            }
            const uint_t* uv = reinterpret_cast<const uint_t*>(&u1);
            #pragma unroll
            for (int j = 0; j < 4; ++j) {
                acc[8+2*j+0] += wsc * bf2f(uv[j] & 0xffffu);
                acc[8+2*j+1] += wsc * bf2f(uv[j] >> 16);
            }
        }

    const float inv = 1.0f / ltot;
    float* op = Out + ((size_t)(batch * NT) + qt * 64 + row) * DK + d0;
    #pragma unroll
    for (int j = 0; j < 16; ++j) op[j] = acc[j] * inv;
}

extern "C" void kernel_launch(void* const* d_in, const int* in_sizes, int n_in,
                              void* d_out, int out_size, void* d_ws, size_t ws_size,
                              hipStream_t stream) {
    const float* X  = (const float*)d_in[0];
    const float* Wq = (const float*)d_in[1];
    const float* bq = (const float*)d_in[2];
    const float* Wk = (const float*)d_in[3];
    const float* bk = (const float*)d_in[4];
    const float* Wv = (const float*)d_in[5];
    const float* bv = (const float*)d_in[6];
    float* Out = (float*)d_out;
    ushort_t* QKV = (ushort_t*)d_ws;                 // Q | K | V^T, each BT*DK bf16
    char* Pbase   = (char*)d_ws + QKV_BYTES;         // 1120 slots x 8704 B (~9.7 MB)
    ushort_t* WtP = (ushort_t*)d_out;                // fragment-packed W (384 KB),
                                                     // consumed by proj, overwritten by attn

    wt_prep_kernel<<<96, 256, 0, stream>>>(Wq, Wk, Wv, WtP);
    qkv_mfma_kernel<<<256, 512, 0, stream>>>(X, WtP, bq, bk, bv, QKV);
    attn_seg_kernel<<<576, 256, 0, stream>>>(QKV, Out, Pbase);
    attn_combine_kernel<<<224, 256, 0, stream>>>(Pbase, Out);
}